// Round 1
// baseline (585.002 us; speedup 1.0000x reference)
//
#include <hip/hip_runtime.h>
#include <math.h>

using bf16x8 = __attribute__((ext_vector_type(8))) short;
using f32x4  = __attribute__((ext_vector_type(4))) float;
using u16x8  = __attribute__((ext_vector_type(8))) unsigned short;
using u16x4  = __attribute__((ext_vector_type(4))) unsigned short;

constexpr int Bb = 4, Tt = 2048, Ee = 1024, Hh = 16;
constexpr int Mm = Bb * Tt;   // 8192
constexpr int E3 = 3 * Ee;    // 3072

__device__ __forceinline__ unsigned short f2bf(float f) {
  union { float f; unsigned int u; } c; c.f = f;
  unsigned int u = c.u;
  u += 0x7fffu + ((u >> 16) & 1u);   // RNE
  return (unsigned short)(u >> 16);
}

__device__ __forceinline__ f32x4 mfma16(bf16x8 a, bf16x8 b, f32x4 c) {
  return __builtin_amdgcn_mfma_f32_16x16x32_bf16(a, b, c, 0, 0, 0);
}

__device__ __forceinline__ void gload_lds16(const unsigned short* g, unsigned short* l) {
  __builtin_amdgcn_global_load_lds(
      (const __attribute__((address_space(1))) unsigned int*)g,
      (__attribute__((address_space(3))) unsigned int*)l, 16, 0, 0);
}

// ---------------------------------------------------------------------------
// fused fp32 -> bf16 conversion for all three inputs (one launch)
// ---------------------------------------------------------------------------
__global__ void cvt_all(const float* __restrict__ q, const float* __restrict__ iw,
                        const float* __restrict__ ow, unsigned short* __restrict__ qb,
                        unsigned short* __restrict__ wib, unsigned short* __restrict__ wob) {
  constexpr int nQ = Mm * Ee / 8, nI = E3 * Ee / 8, nO = Ee * Ee / 8;
  int i = blockIdx.x * 256 + threadIdx.x;
  const float* in; unsigned short* out;
  if (i < nQ) { in = q; out = qb; }
  else if (i < nQ + nI) { in = iw; out = wib; i -= nQ; }
  else if (i < nQ + nI + nO) { in = ow; out = wob; i -= nQ + nI; }
  else return;
  const float4* p = (const float4*)in + (size_t)i * 2;
  const float4 a = p[0], b = p[1];
  u16x8 r = { f2bf(a.x), f2bf(a.y), f2bf(a.z), f2bf(a.w),
              f2bf(b.x), f2bf(b.y), f2bf(b.z), f2bf(b.w) };
  *(u16x8*)(out + (size_t)i * 8) = r;
}

// ---------------------------------------------------------------------------
// C[M,N] = A[M,K] * Bw[N,K]^T + bias  (bf16 MFMA, m97-style)
// QSCALE: cols<1024 (q part) scaled by log2(e)/8 after bias (exp2 trick).
// ---------------------------------------------------------------------------
template <bool OUT_BF16, bool QSCALE>
__global__ __launch_bounds__(256, 2)
void gemm_bt(const unsigned short* __restrict__ A, const unsigned short* __restrict__ Bw,
             const float* __restrict__ bias, void* __restrict__ Cout, int N, int K) {
  __shared__ alignas(16) unsigned short As[128 * 32];
  __shared__ alignas(16) unsigned short Bs[128 * 32];
  const int tid = threadIdx.x;
  const int wave = tid >> 6, lane = tid & 63;
  const int l15 = lane & 15, quad = lane >> 4;
  const int wr = wave >> 1, wc = wave & 1;
  const int row0 = blockIdx.y * 128, col0 = blockIdx.x * 128;
  const int srow = lane >> 2, sslot = lane & 3;

  f32x4 acc[4][4];
#pragma unroll
  for (int i = 0; i < 4; ++i)
#pragma unroll
    for (int j = 0; j < 4; ++j) acc[i][j] = f32x4{0.f, 0.f, 0.f, 0.f};

  for (int k0 = 0; k0 < K; k0 += 32) {
#pragma unroll
    for (int t = 0; t < 2; ++t) {
      const int rA = wave * 32 + t * 16 + srow;          // 0..127
      const int g = sslot ^ ((rA >> 1) & 3);             // swizzled global chunk
      gload_lds16(A  + (size_t)(row0 + rA) * K + k0 + g * 8, &As[(wave * 32 + t * 16) * 32]);
      gload_lds16(Bw + (size_t)(col0 + rA) * K + k0 + g * 8, &Bs[(wave * 32 + t * 16) * 32]);
    }
    __syncthreads();

    bf16x8 af[4], bfr[4];
#pragma unroll
    for (int mi = 0; mi < 4; ++mi) {
      const int m = wr * 64 + mi * 16 + l15;
      af[mi] = *(const bf16x8*)&As[m * 32 + (quad ^ ((m >> 1) & 3)) * 8];
    }
#pragma unroll
    for (int ni = 0; ni < 4; ++ni) {
      const int n = wc * 64 + ni * 16 + l15;
      bfr[ni] = *(const bf16x8*)&Bs[n * 32 + (quad ^ ((n >> 1) & 3)) * 8];
    }
#pragma unroll
    for (int mi = 0; mi < 4; ++mi)
#pragma unroll
      for (int ni = 0; ni < 4; ++ni) acc[mi][ni] = mfma16(af[mi], bfr[ni], acc[mi][ni]);
    __syncthreads();
  }

#pragma unroll
  for (int mi = 0; mi < 4; ++mi)
#pragma unroll
    for (int ni = 0; ni < 4; ++ni) {
      const int col = col0 + wc * 64 + ni * 16 + l15;
      const float bv = bias[col];
      const float scale = (QSCALE && col < 1024) ? 0.18033688f : 1.0f;  // log2(e)/8
#pragma unroll
      for (int r = 0; r < 4; ++r) {
        const int row = row0 + wr * 64 + mi * 16 + quad * 4 + r;
        float v = (acc[mi][ni][r] + bv) * scale;
        if (OUT_BF16)
          ((unsigned short*)Cout)[(size_t)row * N + col] = f2bf(v);
        else
          ((float*)Cout)[(size_t)row * N + col] = v;
      }
    }
}

// ---------------------------------------------------------------------------
// V transpose: vt[b][h][d][t] <- qkv v-part [b][t][2048 + h*64 + d]
// ---------------------------------------------------------------------------
__global__ __launch_bounds__(256, 2)
void transpose_v(const unsigned short* __restrict__ qkv, unsigned short* __restrict__ vt) {
  __shared__ unsigned short L[128][66];
  const int tid = threadIdx.x;
  const int bh = blockIdx.x, b = bh >> 4, h = bh & 15;
  const int t0 = blockIdx.y * 128;
#pragma unroll
  for (int p = 0; p < 8; ++p) {
    const int tl = p * 16 + (tid >> 4);
    const int d = (tid & 15) * 4;
    *(u16x4*)&L[tl][d] = *(const u16x4*)(qkv + (size_t)(b * Tt + t0 + tl) * E3 + 2 * Ee + h * 64 + d);
  }
  __syncthreads();
#pragma unroll
  for (int p = 0; p < 8; ++p) {
    const int dw = (tid >> 5) * 8 + p;
    const int tw = (tid & 31) * 4;
    u16x4 w = { L[tw][dw], L[tw + 1][dw], L[tw + 2][dw], L[tw + 3][dw] };
    *(u16x4*)(vt + ((size_t)bh * 64 + dw) * Tt + t0 + tw) = w;
  }
}

// ---------------------------------------------------------------------------
// Fused attention, sub-tile software pipeline. Wave = 32 q-rows x 2048 keys,
// barrier-free, per-wave-private LDS P slab (32x64 bf16, XOR-swizzled).
// Occupancy change vs previous round: 64->32 q-rows/wave doubles the wave
// count (1024 blocks -> 4 blocks/CU, 4 waves/SIMD) at identical total
// instruction work; per-wave state halves (VGPR ~65, LDS 16 KiB/block).
// Key stream processed as 128 sub-tiles of 16 keys. Each sub-step:
//   (A) exp2/pack/ds_write of the PREVIOUS sub-tile's scores  [VALU pipe]
//   (B) S^T MFMAs of the CURRENT sub-tile                     [MFMA pipe]
// -> independent chains, co-issued. PV(j) at each 64-key tile seam, placed
// AFTER the next tile's first S-MFMAs so the LDS write->read wait is covered.
// kb[ki]/vb reloads sit >=4 sub-steps ahead of use. l = P.ones MFMA.
// ---------------------------------------------------------------------------
__global__ __launch_bounds__(256, 4)
void attn_mfma6(const unsigned short* __restrict__ qkv,
                const unsigned short* __restrict__ vt,
                unsigned short* __restrict__ ctx) {
  __shared__ alignas(16) unsigned short Ps[4 * 2048];  // per-wave 32x64 bf16
  const int tid = threadIdx.x;
  const int wave = tid >> 6, lane = tid & 63;
  const int l15 = lane & 15, quad = lane >> 4;
  const int bh = blockIdx.x, b = bh >> 4, h = bh & 15;
  const int q0 = blockIdx.y * 128 + wave * 32;
  unsigned short* const ps = &Ps[wave * 2048];
  const int swz = l15 & 14;

  // Q fragments (B operand): q = q0 + qi*16 + l15, d = kf*32 + quad*8
  bf16x8 qa[2][2];
#pragma unroll
  for (int qi = 0; qi < 2; ++qi)
#pragma unroll
    for (int kf = 0; kf < 2; ++kf)
      qa[qi][kf] = *(const bf16x8*)(qkv +
          (size_t)(b * Tt + q0 + qi * 16 + l15) * E3 + h * 64 + kf * 32 + quad * 8);

  f32x4 o[2][4], ol[2];
#pragma unroll
  for (int qi = 0; qi < 2; ++qi) {
    ol[qi] = f32x4{0.f, 0.f, 0.f, 0.f};
#pragma unroll
    for (int di = 0; di < 4; ++di) o[qi][di] = f32x4{0.f, 0.f, 0.f, 0.f};
  }
  bf16x8 ones;
#pragma unroll
  for (int i = 0; i < 8; ++i) ones[i] = (short)0x3F80;  // bf16 1.0

  const unsigned short* kp = qkv + (size_t)(b * Tt + l15) * E3 + Ee + h * 64 + quad * 8;
  const unsigned short* vp = vt + ((size_t)bh * 64 + l15) * Tt + quad * 8;

  bf16x8 kb[4][2], vb[4][2];
#pragma unroll
  for (int ki = 0; ki < 4; ++ki)
#pragma unroll
    for (int kf = 0; kf < 2; ++kf)
      kb[ki][kf] = *(const bf16x8*)(kp + (size_t)ki * 16 * E3 + kf * 32);
#pragma unroll
  for (int di = 0; di < 4; ++di)
#pragma unroll
    for (int kf = 0; kf < 2; ++kf)
      vb[di][kf] = *(const bf16x8*)(vp + di * 16 * Tt + kf * 32);
  kp += 64 * E3;   // -> tile 1 (reload source)
  vp += 64;        // -> tile 1 (next vb reload)

  f32x4 sp[2], sn[2];

  // exp/pack/write previous sub-tile scores into slot (0..3) of the P slab
  auto expwrite = [&](int slot) __attribute__((always_inline)) {
#pragma unroll
    for (int qi = 0; qi < 2; ++qi) {
      const float e0 = __builtin_amdgcn_exp2f(sp[qi][0]);
      const float e1 = __builtin_amdgcn_exp2f(sp[qi][1]);
      const float e2 = __builtin_amdgcn_exp2f(sp[qi][2]);
      const float e3 = __builtin_amdgcn_exp2f(sp[qi][3]);
      uint2 w;  // truncate-to-bf16 pairs (bias cancels: denom uses same P)
      w.x = __builtin_amdgcn_perm(__float_as_uint(e1), __float_as_uint(e0), 0x07060302u);
      w.y = __builtin_amdgcn_perm(__float_as_uint(e3), __float_as_uint(e2), 0x07060302u);
      *(uint2*)(ps + (qi * 16 + l15) * 64 + (((slot * 4 + quad) ^ swz) << 2)) = w;
    }
  };
  // S^T MFMAs for current sub-tile (kb row ki)
  auto Sstep = [&](int ki) __attribute__((always_inline)) {
#pragma unroll
    for (int qi = 0; qi < 2; ++qi) {
      sn[qi] = mfma16(kb[ki][0], qa[qi][0], f32x4{0.f, 0.f, 0.f, 0.f});
      sn[qi] = mfma16(kb[ki][1], qa[qi][1], sn[qi]);
    }
  };
  auto copy_sp = [&]() __attribute__((always_inline)) {
#pragma unroll
    for (int qi = 0; qi < 2; ++qi) sp[qi] = sn[qi];
  };
  // PV for the tile whose P slab is complete; optional vb reload (next tile)
  auto pvstep = [&](bool reload_vb) __attribute__((always_inline)) {
#pragma unroll
    for (int qi = 0; qi < 2; ++qi) {
      bf16x8 pa0 = *(const bf16x8*)(ps + (qi * 16 + l15) * 64 + (((quad * 2) ^ swz) << 2));
      bf16x8 pa1 = *(const bf16x8*)(ps + (qi * 16 + l15) * 64 + (((8 + quad * 2) ^ swz) << 2));
      ol[qi] = mfma16(pa0, ones, ol[qi]);
      ol[qi] = mfma16(pa1, ones, ol[qi]);
#pragma unroll
      for (int di = 0; di < 4; ++di) {
        o[qi][di] = mfma16(pa0, vb[di][0], o[qi][di]);
        o[qi][di] = mfma16(pa1, vb[di][1], o[qi][di]);
      }
    }
    if (reload_vb) {
#pragma unroll
      for (int di = 0; di < 4; ++di)
#pragma unroll
        for (int kf = 0; kf < 2; ++kf)
          vb[di][kf] = *(const bf16x8*)(vp + di * 16 * Tt + kf * 32);
      vp += 64;
    }
  };

  // prologue: S(0,0); kb[0] -> tile 1
  Sstep(0); copy_sp();
  kb[0][0] = *(const bf16x8*)(kp);
  kb[0][1] = *(const bf16x8*)(kp + 32);

  for (int j = 0; j < 31; ++j) {
    // (j,1)
    expwrite(0);                       // slot (j,0)
    Sstep(1);
    kb[1][0] = *(const bf16x8*)(kp + (size_t)16 * E3);
    kb[1][1] = *(const bf16x8*)(kp + (size_t)16 * E3 + 32);
    copy_sp();
    // (j,2)
    expwrite(1);
    Sstep(2);
    kb[2][0] = *(const bf16x8*)(kp + (size_t)32 * E3);
    kb[2][1] = *(const bf16x8*)(kp + (size_t)32 * E3 + 32);
    copy_sp();
    // (j,3)
    expwrite(2);
    Sstep(3);
    kb[3][0] = *(const bf16x8*)(kp + (size_t)48 * E3);
    kb[3][1] = *(const bf16x8*)(kp + (size_t)48 * E3 + 32);
    kp += 64 * E3;                     // -> tile j+2
    copy_sp();
    // seam: (j+1,0) then PV(j)
    expwrite(3);                       // completes P(j)
    Sstep(0);                          // S(j+1,0): MFMA cover for the LDS wait
    if (j < 30) {
      kb[0][0] = *(const bf16x8*)(kp);
      kb[0][1] = *(const bf16x8*)(kp + 32);
    }
    copy_sp();
    pvstep(true);                      // PV(j); vb -> tile j+1
  }
  // tail: tile 31 (sp holds (31,0))
  expwrite(0); Sstep(1); copy_sp();
  expwrite(1); Sstep(2); copy_sp();
  expwrite(2); Sstep(3); copy_sp();
  expwrite(3);
  pvstep(false);                       // PV(31)

  // epilogue: divide by l (same layout), store bf16 ctx
#pragma unroll
  for (int qi = 0; qi < 2; ++qi) {
    f32x4 inv;
#pragma unroll
    for (int r = 0; r < 4; ++r) inv[r] = 1.0f / ol[qi][r];
#pragma unroll
    for (int di = 0; di < 4; ++di)
#pragma unroll
      for (int r = 0; r < 4; ++r)
        ctx[(size_t)(b * Tt + q0 + qi * 16 + quad * 4 + r) * Ee + h * 64 + di * 16 + l15] =
            f2bf(o[qi][di][r] * inv[r]);
  }
}

// ---------------------------------------------------------------------------
extern "C" void kernel_launch(void* const* d_in, const int* in_sizes, int n_in,
                              void* d_out, int out_size, void* d_ws, size_t ws_size,
                              hipStream_t stream) {
  const float* query = (const float*)d_in[0];
  const float* in_w  = (const float*)d_in[1];
  const float* in_b  = (const float*)d_in[2];
  const float* out_w = (const float*)d_in[3];
  const float* out_b = (const float*)d_in[4];
  float* out = (float*)d_out;

  char* w = (char*)d_ws;
  unsigned short* qkvb = (unsigned short*)(w);                 // 48 MiB
  unsigned short* ctxb = (unsigned short*)(w + 50331648);      // 16 MiB
  unsigned short* qb   = (unsigned short*)(w + 67108864);      // 16 MiB
  unsigned short* wib  = (unsigned short*)(w + 83886080);      // 6 MiB
  unsigned short* wob  = (unsigned short*)(w + 90177536);      // 2 MiB
  unsigned short* vtb  = (unsigned short*)(w + 92274688);      // 16 MiB

  // 0) all fp32->bf16 conversions in one launch
  cvt_all<<<6144, 256, 0, stream>>>(query, in_w, out_w, qb, wib, wob);
  // 1) qkv = query @ in_w^T + in_b  (q part pre-scaled by log2e/8, bf16)
  gemm_bt<true, true><<<dim3(E3 / 128, Mm / 128), 256, 0, stream>>>(qb, wib, in_b, qkvb, E3, Ee);
  // 1b) pre-transpose V: vt[b][h][d][t]
  transpose_v<<<dim3(Bb * Hh, Tt / 128), 256, 0, stream>>>(qkvb, vtb);
  // 2) fused attention (32 q-rows/wave, 4 blocks/CU) -> ctx (bf16, [B,T,E])
  attn_mfma6<<<dim3(Bb * Hh, Tt / 128), 256, 0, stream>>>(qkvb, vtb, ctxb);
  // 3) out = ctx @ out_w^T + out_b  (fp32 out)
  gemm_bt<false, false><<<dim3(Ee / 128, Mm / 128), 256, 0, stream>>>(ctxb, wob, out_b, out, Ee, Ee);
}

// Round 2
// 319.590 us; speedup vs baseline: 1.8305x; 1.8305x over previous
//
#include <hip/hip_runtime.h>
#include <math.h>

using bf16x8 = __attribute__((ext_vector_type(8))) short;
using f32x4  = __attribute__((ext_vector_type(4))) float;
using u16x8  = __attribute__((ext_vector_type(8))) unsigned short;
using u16x4  = __attribute__((ext_vector_type(4))) unsigned short;

constexpr int Bb = 4, Tt = 2048, Ee = 1024, Hh = 16;
constexpr int Mm = Bb * Tt;   // 8192
constexpr int E3 = 3 * Ee;    // 3072

__device__ __forceinline__ unsigned short f2bf(float f) {
  union { float f; unsigned int u; } c; c.f = f;
  unsigned int u = c.u;
  u += 0x7fffu + ((u >> 16) & 1u);   // RNE
  return (unsigned short)(u >> 16);
}

__device__ __forceinline__ f32x4 mfma16(bf16x8 a, bf16x8 b, f32x4 c) {
  return __builtin_amdgcn_mfma_f32_16x16x32_bf16(a, b, c, 0, 0, 0);
}

__device__ __forceinline__ void gload_lds16(const unsigned short* g, unsigned short* l) {
  __builtin_amdgcn_global_load_lds(
      (const __attribute__((address_space(1))) unsigned int*)g,
      (__attribute__((address_space(3))) unsigned int*)l, 16, 0, 0);
}

// ---------------------------------------------------------------------------
// fused fp32 -> bf16 conversion for all three inputs (one launch)
// ---------------------------------------------------------------------------
__global__ void cvt_all(const float* __restrict__ q, const float* __restrict__ iw,
                        const float* __restrict__ ow, unsigned short* __restrict__ qb,
                        unsigned short* __restrict__ wib, unsigned short* __restrict__ wob) {
  constexpr int nQ = Mm * Ee / 8, nI = E3 * Ee / 8, nO = Ee * Ee / 8;
  int i = blockIdx.x * 256 + threadIdx.x;
  const float* in; unsigned short* out;
  if (i < nQ) { in = q; out = qb; }
  else if (i < nQ + nI) { in = iw; out = wib; i -= nQ; }
  else if (i < nQ + nI + nO) { in = ow; out = wob; i -= nQ + nI; }
  else return;
  const float4* p = (const float4*)in + (size_t)i * 2;
  const float4 a = p[0], b = p[1];
  u16x8 r = { f2bf(a.x), f2bf(a.y), f2bf(a.z), f2bf(a.w),
              f2bf(b.x), f2bf(b.y), f2bf(b.z), f2bf(b.w) };
  *(u16x8*)(out + (size_t)i * 8) = r;
}

// ---------------------------------------------------------------------------
// C[M,N] = A[M,K] * Bw[N,K]^T + bias  (bf16 MFMA, m97-style)
// QSCALE: cols<1024 (q part) scaled by log2(e)/8 after bias (exp2 trick).
// ---------------------------------------------------------------------------
template <bool OUT_BF16, bool QSCALE>
__global__ __launch_bounds__(256, 2)
void gemm_bt(const unsigned short* __restrict__ A, const unsigned short* __restrict__ Bw,
             const float* __restrict__ bias, void* __restrict__ Cout, int N, int K) {
  __shared__ alignas(16) unsigned short As[128 * 32];
  __shared__ alignas(16) unsigned short Bs[128 * 32];
  const int tid = threadIdx.x;
  const int wave = tid >> 6, lane = tid & 63;
  const int l15 = lane & 15, quad = lane >> 4;
  const int wr = wave >> 1, wc = wave & 1;
  const int row0 = blockIdx.y * 128, col0 = blockIdx.x * 128;
  const int srow = lane >> 2, sslot = lane & 3;

  f32x4 acc[4][4];
#pragma unroll
  for (int i = 0; i < 4; ++i)
#pragma unroll
    for (int j = 0; j < 4; ++j) acc[i][j] = f32x4{0.f, 0.f, 0.f, 0.f};

  for (int k0 = 0; k0 < K; k0 += 32) {
#pragma unroll
    for (int t = 0; t < 2; ++t) {
      const int rA = wave * 32 + t * 16 + srow;          // 0..127
      const int g = sslot ^ ((rA >> 1) & 3);             // swizzled global chunk
      gload_lds16(A  + (size_t)(row0 + rA) * K + k0 + g * 8, &As[(wave * 32 + t * 16) * 32]);
      gload_lds16(Bw + (size_t)(col0 + rA) * K + k0 + g * 8, &Bs[(wave * 32 + t * 16) * 32]);
    }
    __syncthreads();

    bf16x8 af[4], bfr[4];
#pragma unroll
    for (int mi = 0; mi < 4; ++mi) {
      const int m = wr * 64 + mi * 16 + l15;
      af[mi] = *(const bf16x8*)&As[m * 32 + (quad ^ ((m >> 1) & 3)) * 8];
    }
#pragma unroll
    for (int ni = 0; ni < 4; ++ni) {
      const int n = wc * 64 + ni * 16 + l15;
      bfr[ni] = *(const bf16x8*)&Bs[n * 32 + (quad ^ ((n >> 1) & 3)) * 8];
    }
#pragma unroll
    for (int mi = 0; mi < 4; ++mi)
#pragma unroll
      for (int ni = 0; ni < 4; ++ni) acc[mi][ni] = mfma16(af[mi], bfr[ni], acc[mi][ni]);
    __syncthreads();
  }

#pragma unroll
  for (int mi = 0; mi < 4; ++mi)
#pragma unroll
    for (int ni = 0; ni < 4; ++ni) {
      const int col = col0 + wc * 64 + ni * 16 + l15;
      const float bv = bias[col];
      const float scale = (QSCALE && col < 1024) ? 0.18033688f : 1.0f;  // log2(e)/8
#pragma unroll
      for (int r = 0; r < 4; ++r) {
        const int row = row0 + wr * 64 + mi * 16 + quad * 4 + r;
        float v = (acc[mi][ni][r] + bv) * scale;
        if (OUT_BF16)
          ((unsigned short*)Cout)[(size_t)row * N + col] = f2bf(v);
        else
          ((float*)Cout)[(size_t)row * N + col] = v;
      }
    }
}

// ---------------------------------------------------------------------------
// V transpose: vt[b][h][d][t] <- qkv v-part [b][t][2048 + h*64 + d]
// ---------------------------------------------------------------------------
__global__ __launch_bounds__(256, 2)
void transpose_v(const unsigned short* __restrict__ qkv, unsigned short* __restrict__ vt) {
  __shared__ unsigned short L[128][66];
  const int tid = threadIdx.x;
  const int bh = blockIdx.x, b = bh >> 4, h = bh & 15;
  const int t0 = blockIdx.y * 128;
#pragma unroll
  for (int p = 0; p < 8; ++p) {
    const int tl = p * 16 + (tid >> 4);
    const int d = (tid & 15) * 4;
    *(u16x4*)&L[tl][d] = *(const u16x4*)(qkv + (size_t)(b * Tt + t0 + tl) * E3 + 2 * Ee + h * 64 + d);
  }
  __syncthreads();
#pragma unroll
  for (int p = 0; p < 8; ++p) {
    const int dw = (tid >> 5) * 8 + p;
    const int tw = (tid & 31) * 4;
    u16x4 w = { L[tw][dw], L[tw + 1][dw], L[tw + 2][dw], L[tw + 3][dw] };
    *(u16x4*)(vt + ((size_t)bh * 64 + dw) * Tt + t0 + tw) = w;
  }
}

// ---------------------------------------------------------------------------
// Fused attention, sub-tile software pipeline. 512-thread blocks, 8 waves.
// Wave pair (qgroup = wave>>1) covers 64 q-rows; the two waves of a pair
// split the 2048 keys in half (khalf = wave&1) -> per-wave state identical
// to the proven 64-row kernel (VGPR ~120, no spill), but 2x the wave count:
// 512 blocks x 8 waves = 4096 waves = 4 waves/SIMD (vs 2 before).
// K/V total reads unchanged (disjoint halves); partial o/l combined in-LDS
// at the end (no running max exists -> partials simply add).
// Main loop is instruction-identical to the round-0 kernel, 16 tiles not 32.
// ---------------------------------------------------------------------------
__global__ __launch_bounds__(512, 2)
void attn_mfma6(const unsigned short* __restrict__ qkv,
                const unsigned short* __restrict__ vt,
                unsigned short* __restrict__ ctx) {
  __shared__ alignas(16) unsigned short Ps[8 * 4096];  // per-wave 64x64 bf16 (8 KB each)
  __shared__ float olpart[4][64];                      // per-pair l exchange
  const int tid = threadIdx.x;
  const int wave = tid >> 6, lane = tid & 63;
  const int l15 = lane & 15, quad = lane >> 4;
  const int qgroup = wave >> 1, khalf = wave & 1;
  const int bh = blockIdx.x, b = bh >> 4, h = bh & 15;
  const int q0 = blockIdx.y * 256 + qgroup * 64;
  unsigned short* const ps = &Ps[wave * 4096];
  const int swz = l15 & 14;

  // Q fragments (B operand): q = q0 + qi*16 + l15, d = kf*32 + quad*8
  bf16x8 qa[4][2];
#pragma unroll
  for (int qi = 0; qi < 4; ++qi)
#pragma unroll
    for (int kf = 0; kf < 2; ++kf)
      qa[qi][kf] = *(const bf16x8*)(qkv +
          (size_t)(b * Tt + q0 + qi * 16 + l15) * E3 + h * 64 + kf * 32 + quad * 8);

  f32x4 o[4][4], ol[4];
#pragma unroll
  for (int qi = 0; qi < 4; ++qi) {
    ol[qi] = f32x4{0.f, 0.f, 0.f, 0.f};
#pragma unroll
    for (int di = 0; di < 4; ++di) o[qi][di] = f32x4{0.f, 0.f, 0.f, 0.f};
  }
  bf16x8 ones;
#pragma unroll
  for (int i = 0; i < 8; ++i) ones[i] = (short)0x3F80;  // bf16 1.0

  // key stream: this wave handles keys [khalf*1024, khalf*1024 + 1024)
  const unsigned short* kp = qkv + (size_t)(b * Tt + khalf * 1024 + l15) * E3 + Ee + h * 64 + quad * 8;
  const unsigned short* vp = vt + ((size_t)bh * 64 + l15) * Tt + khalf * 1024 + quad * 8;

  bf16x8 kb[4][2], vb[4][2];
#pragma unroll
  for (int ki = 0; ki < 4; ++ki)
#pragma unroll
    for (int kf = 0; kf < 2; ++kf)
      kb[ki][kf] = *(const bf16x8*)(kp + (size_t)ki * 16 * E3 + kf * 32);
#pragma unroll
  for (int di = 0; di < 4; ++di)
#pragma unroll
    for (int kf = 0; kf < 2; ++kf)
      vb[di][kf] = *(const bf16x8*)(vp + di * 16 * Tt + kf * 32);
  kp += 64 * E3;   // -> tile 1 (reload source)
  vp += 64;        // -> tile 1 (next vb reload)

  f32x4 sp[4], sn[4];

  // exp/pack/write previous sub-tile scores into slot (0..3) of the P slab
  auto expwrite = [&](int slot) __attribute__((always_inline)) {
#pragma unroll
    for (int qi = 0; qi < 4; ++qi) {
      const float e0 = __builtin_amdgcn_exp2f(sp[qi][0]);
      const float e1 = __builtin_amdgcn_exp2f(sp[qi][1]);
      const float e2 = __builtin_amdgcn_exp2f(sp[qi][2]);
      const float e3 = __builtin_amdgcn_exp2f(sp[qi][3]);
      uint2 w;  // truncate-to-bf16 pairs (bias cancels: denom uses same P)
      w.x = __builtin_amdgcn_perm(__float_as_uint(e1), __float_as_uint(e0), 0x07060302u);
      w.y = __builtin_amdgcn_perm(__float_as_uint(e3), __float_as_uint(e2), 0x07060302u);
      *(uint2*)(ps + (qi * 16 + l15) * 64 + (((slot * 4 + quad) ^ swz) << 2)) = w;
    }
  };
  // S^T MFMAs for current sub-tile (kb row ki)
  auto Sstep = [&](int ki) __attribute__((always_inline)) {
#pragma unroll
    for (int qi = 0; qi < 4; ++qi) {
      sn[qi] = mfma16(kb[ki][0], qa[qi][0], f32x4{0.f, 0.f, 0.f, 0.f});
      sn[qi] = mfma16(kb[ki][1], qa[qi][1], sn[qi]);
    }
  };
  auto copy_sp = [&]() __attribute__((always_inline)) {
#pragma unroll
    for (int qi = 0; qi < 4; ++qi) sp[qi] = sn[qi];
  };
  // PV for the tile whose P slab is complete; optional vb reload (next tile)
  auto pvstep = [&](bool reload_vb) __attribute__((always_inline)) {
#pragma unroll
    for (int qi = 0; qi < 4; ++qi) {
      bf16x8 pa0 = *(const bf16x8*)(ps + (qi * 16 + l15) * 64 + (((quad * 2) ^ swz) << 2));
      bf16x8 pa1 = *(const bf16x8*)(ps + (qi * 16 + l15) * 64 + (((8 + quad * 2) ^ swz) << 2));
      ol[qi] = mfma16(pa0, ones, ol[qi]);
      ol[qi] = mfma16(pa1, ones, ol[qi]);
#pragma unroll
      for (int di = 0; di < 4; ++di) {
        o[qi][di] = mfma16(pa0, vb[di][0], o[qi][di]);
        o[qi][di] = mfma16(pa1, vb[di][1], o[qi][di]);
      }
    }
    if (reload_vb) {
#pragma unroll
      for (int di = 0; di < 4; ++di)
#pragma unroll
        for (int kf = 0; kf < 2; ++kf)
          vb[di][kf] = *(const bf16x8*)(vp + di * 16 * Tt + kf * 32);
      vp += 64;
    }
  };

  // prologue: S(0,0); kb[0] -> tile 1
  Sstep(0); copy_sp();
  kb[0][0] = *(const bf16x8*)(kp);
  kb[0][1] = *(const bf16x8*)(kp + 32);

  for (int j = 0; j < 15; ++j) {
    // (j,1)
    expwrite(0);                       // slot (j,0)
    Sstep(1);
    kb[1][0] = *(const bf16x8*)(kp + (size_t)16 * E3);
    kb[1][1] = *(const bf16x8*)(kp + (size_t)16 * E3 + 32);
    copy_sp();
    // (j,2)
    expwrite(1);
    Sstep(2);
    kb[2][0] = *(const bf16x8*)(kp + (size_t)32 * E3);
    kb[2][1] = *(const bf16x8*)(kp + (size_t)32 * E3 + 32);
    copy_sp();
    // (j,3)
    expwrite(2);
    Sstep(3);
    kb[3][0] = *(const bf16x8*)(kp + (size_t)48 * E3);
    kb[3][1] = *(const bf16x8*)(kp + (size_t)48 * E3 + 32);
    kp += 64 * E3;                     // -> tile j+2
    copy_sp();
    // seam: (j+1,0) then PV(j)
    expwrite(3);                       // completes P(j)
    Sstep(0);                          // S(j+1,0): MFMA cover for the LDS wait
    if (j < 14) {
      kb[0][0] = *(const bf16x8*)(kp);
      kb[0][1] = *(const bf16x8*)(kp + 32);
    }
    copy_sp();
    pvstep(true);                      // PV(j); vb -> tile j+1
  }
  // tail: tile 15 (sp holds (15,0))
  expwrite(0); Sstep(1); copy_sp();
  expwrite(1); Sstep(2); copy_sp();
  expwrite(2); Sstep(3); copy_sp();
  expwrite(3);
  pvstep(false);                       // PV(15)

  // -------------------------------------------------------------------------
  // combine the two key-halves of each wave pair in LDS, then store.
  // Pair slab = the pair's two 8 KB P slabs (16 KB = 4096 floats), reused.
  // Layout: [ (qi*4+di)*4 + r ][ lane ] floats -> lane-contiguous, no conflicts.
  // -------------------------------------------------------------------------
  __syncthreads();
  float* const po = (float*)&Ps[(size_t)qgroup * 8192];
  if (khalf) {
#pragma unroll
    for (int qi = 0; qi < 4; ++qi)
#pragma unroll
      for (int di = 0; di < 4; ++di)
#pragma unroll
        for (int r = 0; r < 4; ++r)
          po[((qi * 4 + di) * 4 + r) * 64 + lane] = o[qi][di][r];
    if (l15 == 0)
#pragma unroll
      for (int qi = 0; qi < 4; ++qi)
#pragma unroll
        for (int r = 0; r < 4; ++r)
          olpart[qgroup][qi * 16 + quad * 4 + r] = ol[qi][r];
  }
  __syncthreads();
  if (!khalf) {
#pragma unroll
    for (int qi = 0; qi < 4; ++qi) {
      f32x4 inv;
#pragma unroll
      for (int r = 0; r < 4; ++r)
        inv[r] = 1.0f / (ol[qi][r] + olpart[qgroup][qi * 16 + quad * 4 + r]);
#pragma unroll
      for (int di = 0; di < 4; ++di)
#pragma unroll
        for (int r = 0; r < 4; ++r) {
          const float v = o[qi][di][r] + po[((qi * 4 + di) * 4 + r) * 64 + lane];
          ctx[(size_t)(b * Tt + q0 + qi * 16 + quad * 4 + r) * Ee + h * 64 + di * 16 + l15] =
              f2bf(v * inv[r]);
        }
    }
  }
}

// ---------------------------------------------------------------------------
extern "C" void kernel_launch(void* const* d_in, const int* in_sizes, int n_in,
                              void* d_out, int out_size, void* d_ws, size_t ws_size,
                              hipStream_t stream) {
  const float* query = (const float*)d_in[0];
  const float* in_w  = (const float*)d_in[1];
  const float* in_b  = (const float*)d_in[2];
  const float* out_w = (const float*)d_in[3];
  const float* out_b = (const float*)d_in[4];
  float* out = (float*)d_out;

  char* w = (char*)d_ws;
  unsigned short* qkvb = (unsigned short*)(w);                 // 48 MiB
  unsigned short* ctxb = (unsigned short*)(w + 50331648);      // 16 MiB
  unsigned short* qb   = (unsigned short*)(w + 67108864);      // 16 MiB
  unsigned short* wib  = (unsigned short*)(w + 83886080);      // 6 MiB
  unsigned short* wob  = (unsigned short*)(w + 90177536);      // 2 MiB
  unsigned short* vtb  = (unsigned short*)(w + 92274688);      // 16 MiB

  // 0) all fp32->bf16 conversions in one launch
  cvt_all<<<6144, 256, 0, stream>>>(query, in_w, out_w, qb, wib, wob);
  // 1) qkv = query @ in_w^T + in_b  (q part pre-scaled by log2e/8, bf16)
  gemm_bt<true, true><<<dim3(E3 / 128, Mm / 128), 256, 0, stream>>>(qb, wib, in_b, qkvb, E3, Ee);
  // 1b) pre-transpose V: vt[b][h][d][t]
  transpose_v<<<dim3(Bb * Hh, Tt / 128), 256, 0, stream>>>(qkvb, vtb);
  // 2) fused attention (64 q-rows/wave, key-split pairs, 8 waves/block)
  attn_mfma6<<<dim3(Bb * Hh, Tt / 256), 512, 0, stream>>>(qkvb, vtb, ctxb);
  // 3) out = ctx @ out_w^T + out_b  (fp32 out)
  gemm_bt<false, false><<<dim3(Ee / 128, Mm / 128), 256, 0, stream>>>(ctxb, wob, out_b, out, Ee, Ee);
}